// Round 3
// baseline (993.076 us; speedup 1.0000x reference)
//
#include <hip/hip_runtime.h>
#include <hip/hip_bf16.h>
#include <math.h>

#define EMB 64
#define SEQ 64
#define NH 8
#define DFF 256
#define VOC 32000
#define BATCH 64

using bf16_t = __hip_bfloat16;
typedef __bf16 bf16x8 __attribute__((ext_vector_type(8)));
typedef float f32x4 __attribute__((ext_vector_type(4)));

// ws layout (bytes)
#define WOUTT_OFF 0                     // bf16 [32000][64]  = 4,096,000 B
#define HBF_OFF   4194304               // bf16 [4096][64]   = 524,288 B
#define GSUM_OFF  (4194304 + 524288)    // f32  [4096]       = 16,384 B

// ---------- kernel 0: wout [64][32000] f32 -> woutT [32000][64] bf16 ----------
__global__ __launch_bounds__(256) void k_woutT(const float* __restrict__ wout,
                                               bf16_t* __restrict__ woutT) {
  __shared__ float tile[64 * 65];
  int v0 = blockIdx.x * 64;
  int t = threadIdx.x;
  for (int idx = t; idx < 4096; idx += 256) {
    int e = idx >> 6, c = idx & 63;
    tile[e * 65 + c] = wout[(size_t)e * VOC + v0 + c];
  }
  __syncthreads();
  for (int idx = t; idx < 4096; idx += 256) {
    int c = idx >> 6, e = idx & 63;
    woutT[(size_t)(v0 + c) * 64 + e] = __float2bfloat16(tile[e * 65 + c]);
  }
}

// ---------- small 64x64x64 GEMM helper: out = in(LDS,ld 65) @ W(global 64x64) ----------
template <int OP>  // 0: none, 1: rint
__device__ inline void gemm64t(const float* __restrict__ in, const float* __restrict__ W,
                               const float* __restrict__ bias, float* __restrict__ out,
                               int t) {
  int i = t >> 2, j0 = (t & 3) * 16;
  float acc[16];
#pragma unroll
  for (int j = 0; j < 16; ++j) acc[j] = 0.f;
  for (int k = 0; k < 64; ++k) {
    float a = in[i * 65 + k];
    const float4* wr = (const float4*)(W + k * 64 + j0);
    float4 w0 = wr[0], w1v = wr[1], w2v = wr[2], w3v = wr[3];
    acc[0] += a * w0.x;   acc[1] += a * w0.y;   acc[2] += a * w0.z;   acc[3] += a * w0.w;
    acc[4] += a * w1v.x;  acc[5] += a * w1v.y;  acc[6] += a * w1v.z;  acc[7] += a * w1v.w;
    acc[8] += a * w2v.x;  acc[9] += a * w2v.y;  acc[10] += a * w2v.z; acc[11] += a * w2v.w;
    acc[12] += a * w3v.x; acc[13] += a * w3v.y; acc[14] += a * w3v.z; acc[15] += a * w3v.w;
  }
#pragma unroll
  for (int j = 0; j < 16; ++j) {
    float v = acc[j] + (bias ? bias[j0 + j] : 0.f);
    if (OP == 1) v = rintf(v);
    out[i * 65 + j0 + j] = v;
  }
}

// ---------- kernel 1: full transformer through final LN, one block per batch ----------
__global__ __launch_bounds__(256) void k_former(
    const int* __restrict__ x, const float* __restrict__ emb, const float* __restrict__ pe,
    const float* __restrict__ wq, const float* __restrict__ wk, const float* __restrict__ wv,
    const float* __restrict__ g_h, const float* __restrict__ b_h,
    const float* __restrict__ wo, const float* __restrict__ bo,
    const float* __restrict__ g1, const float* __restrict__ bt1,
    const float* __restrict__ w1, const float* __restrict__ b1f,
    const float* __restrict__ w2, const float* __restrict__ b2f,
    const float* __restrict__ g2, const float* __restrict__ bt2,
    const float* __restrict__ gf, const float* __restrict__ bf_,
    bf16_t* __restrict__ hbf, float* __restrict__ gsums) {
  const int b = blockIdx.x, t = threadIdx.x;
  if (t < 64) gsums[b * 64 + t] = 0.f;  // zero row-sum accumulators (64 blocks x 64 = 4096)

  __shared__ float sm[6 * 64 * 65];   // 99.84 KB
  float* Hs = sm;                      // [64][65]
  float* Qs = sm + 4160;
  float* Ks = sm + 2 * 4160;
  float* Vs = sm + 3 * 4160;
  float* SC = sm + 4 * 4160;
  float* HO = sm + 5 * 4160;
  float* MID = sm + 4160;              // [64][260] overlays Qs..SC (16640 floats)

  // Stage 0: h = emb[x[b]] + pe
  for (int idx = t; idx < 4096; idx += 256) {
    int i = idx >> 6, e = idx & 63;
    int tok = x[b * 64 + i];
    Hs[i * 65 + e] = emb[(size_t)tok * 64 + e] + pe[i * 64 + e];
  }
  __syncthreads();

  // Stage 1: Q, K, V
  gemm64t<0>(Hs, wq, nullptr, Qs, t);
  gemm64t<0>(Hs, wk, nullptr, Ks, t);
  gemm64t<0>(Hs, wv, nullptr, Vs, t);
  __syncthreads();

  // Stage 2: attention per head (causal softmax, round4 on head outputs)
  const float scale = 0.35355339059327373f;  // 1/sqrt(8)
  for (int hh = 0; hh < NH; ++hh) {
    int qc = hh * 8;
    {
      int i = t >> 2, jb = t & 3;
      float qv[8];
#pragma unroll
      for (int d = 0; d < 8; ++d) qv[d] = Qs[i * 65 + qc + d];
      for (int jj = 0; jj < 16; ++jj) {
        int j = jb * 16 + jj;
        float s;
        if (j <= i) {
          s = 0.f;
#pragma unroll
          for (int d = 0; d < 8; ++d) s += qv[d] * Ks[j * 65 + qc + d];
          s *= scale;
        } else {
          s = -INFINITY;
        }
        SC[i * 65 + j] = s;
      }
    }
    __syncthreads();
    if (t < 64) {
      int i = t;
      float m = -INFINITY;
      for (int j = 0; j <= i; ++j) m = fmaxf(m, SC[i * 65 + j]);
      float sum = 0.f;
      for (int j = 0; j <= i; ++j) {
        float e2 = __expf(SC[i * 65 + j] - m);
        SC[i * 65 + j] = e2;
        sum += e2;
      }
      float inv = 1.f / sum;
      for (int j = 0; j <= i; ++j) SC[i * 65 + j] *= inv;
      for (int j = i + 1; j < 64; ++j) SC[i * 65 + j] = 0.f;
    }
    __syncthreads();
    for (int idx = t; idx < 512; idx += 256) {
      int i = idx >> 3, d = idx & 7;
      float o = 0.f;
      for (int j = 0; j < 64; ++j) o += SC[i * 65 + j] * Vs[j * 65 + qc + d];
      HO[i * 65 + qc + d] = rintf(o * 1e4f) / 1e4f;  // round4
    }
    __syncthreads();
  }

  // Stage 3: ln_h = layernorm(HO; g_h,b_h) -> SC ; attn_out = rint(SC@wo+bo) -> HO
  if (t < 64) {
    int i = t;
    float mu = 0.f;
    for (int e = 0; e < 64; ++e) mu += HO[i * 65 + e];
    mu *= (1.f / 64.f);
    float var = 0.f;
    for (int e = 0; e < 64; ++e) { float d = HO[i * 65 + e] - mu; var += d * d; }
    var *= (1.f / 64.f);
    float rs = rsqrtf(var + 1e-5f);
    for (int e = 0; e < 64; ++e) SC[i * 65 + e] = (HO[i * 65 + e] - mu) * rs * g_h[e] + b_h[e];
  }
  __syncthreads();
  gemm64t<1>(SC, wo, bo, HO, t);
  __syncthreads();

  // Stage 4: h1 = layernorm(Hs + HO; g1,bt1) -> Hs
  if (t < 64) {
    int i = t;
    for (int e = 0; e < 64; ++e) Hs[i * 65 + e] += HO[i * 65 + e];
    float mu = 0.f;
    for (int e = 0; e < 64; ++e) mu += Hs[i * 65 + e];
    mu *= (1.f / 64.f);
    float var = 0.f;
    for (int e = 0; e < 64; ++e) { float d = Hs[i * 65 + e] - mu; var += d * d; }
    var *= (1.f / 64.f);
    float rs = rsqrtf(var + 1e-5f);
    for (int e = 0; e < 64; ++e) Hs[i * 65 + e] = (Hs[i * 65 + e] - mu) * rs * g1[e] + bt1[e];
  }
  __syncthreads();

  // Stage 5: MID = relu(Hs @ w1 + b1f)  [64][260 pad]
  {
    int i = t >> 2, jq = t & 3;
    for (int c = 0; c < 4; ++c) {
      int j0 = jq * 64 + c * 16;
      float acc[16];
#pragma unroll
      for (int j = 0; j < 16; ++j) acc[j] = 0.f;
      for (int k = 0; k < 64; ++k) {
        float a = Hs[i * 65 + k];
        const float4* wr = (const float4*)(w1 + (size_t)k * 256 + j0);
        float4 w0 = wr[0], w1v = wr[1], w2v = wr[2], w3v = wr[3];
        acc[0] += a * w0.x;   acc[1] += a * w0.y;   acc[2] += a * w0.z;   acc[3] += a * w0.w;
        acc[4] += a * w1v.x;  acc[5] += a * w1v.y;  acc[6] += a * w1v.z;  acc[7] += a * w1v.w;
        acc[8] += a * w2v.x;  acc[9] += a * w2v.y;  acc[10] += a * w2v.z; acc[11] += a * w2v.w;
        acc[12] += a * w3v.x; acc[13] += a * w3v.y; acc[14] += a * w3v.z; acc[15] += a * w3v.w;
      }
#pragma unroll
      for (int j = 0; j < 16; ++j)
        MID[i * 260 + j0 + j] = fmaxf(acc[j] + b1f[j0 + j], 0.f);
    }
  }
  __syncthreads();

  // Stage 6: ffn_out = MID @ w2 + b2f -> HO
  {
    int i = t >> 2, j0 = (t & 3) * 16;
    float acc[16];
#pragma unroll
    for (int j = 0; j < 16; ++j) acc[j] = 0.f;
    for (int k = 0; k < 256; ++k) {
      float a = MID[i * 260 + k];
      const float4* wr = (const float4*)(w2 + (size_t)k * 64 + j0);
      float4 w0 = wr[0], w1v = wr[1], w2v = wr[2], w3v = wr[3];
      acc[0] += a * w0.x;   acc[1] += a * w0.y;   acc[2] += a * w0.z;   acc[3] += a * w0.w;
      acc[4] += a * w1v.x;  acc[5] += a * w1v.y;  acc[6] += a * w1v.z;  acc[7] += a * w1v.w;
      acc[8] += a * w2v.x;  acc[9] += a * w2v.y;  acc[10] += a * w2v.z; acc[11] += a * w2v.w;
      acc[12] += a * w3v.x; acc[13] += a * w3v.y; acc[14] += a * w3v.z; acc[15] += a * w3v.w;
    }
#pragma unroll
    for (int j = 0; j < 16; ++j) HO[i * 65 + j0 + j] = acc[j] + b2f[j0 + j];
  }
  __syncthreads();

  // Stage 7: h2 = round4(layernorm(Hs + HO; g2,bt2)) -> Hs ; hf = layernorm(Hs; gf,bf) -> SC
  if (t < 64) {
    int i = t;
    for (int e = 0; e < 64; ++e) Hs[i * 65 + e] += HO[i * 65 + e];
    float mu = 0.f;
    for (int e = 0; e < 64; ++e) mu += Hs[i * 65 + e];
    mu *= (1.f / 64.f);
    float var = 0.f;
    for (int e = 0; e < 64; ++e) { float d = Hs[i * 65 + e] - mu; var += d * d; }
    var *= (1.f / 64.f);
    float rs = rsqrtf(var + 1e-5f);
    for (int e = 0; e < 64; ++e)
      Hs[i * 65 + e] = rintf(((Hs[i * 65 + e] - mu) * rs * g2[e] + bt2[e]) * 1e4f) / 1e4f;
    float mu2 = 0.f;
    for (int e = 0; e < 64; ++e) mu2 += Hs[i * 65 + e];
    mu2 *= (1.f / 64.f);
    float var2 = 0.f;
    for (int e = 0; e < 64; ++e) { float d = Hs[i * 65 + e] - mu2; var2 += d * d; }
    var2 *= (1.f / 64.f);
    float rs2 = rsqrtf(var2 + 1e-5f);
    for (int e = 0; e < 64; ++e) SC[i * 65 + e] = (Hs[i * 65 + e] - mu2) * rs2 * gf[e] + bf_[e];
  }
  __syncthreads();

  // Stage 8: hf -> bf16 global
  for (int idx = t; idx < 4096; idx += 256) {
    int i = idx >> 6, e = idx & 63;
    hbf[((size_t)b * 64 + i) * 64 + e] = __float2bfloat16(SC[i * 65 + e]);
  }
}

// ---------- kernel A: per-row sum of exp(logit) over V, MFMA recompute ----------
// grid (8, 64): blockIdx.x = column chunk -> XCD (linear%8 == x), so each XCD's
// L2 holds only its 512 KB woutT slice. 64 rows per block.
__global__ __launch_bounds__(256) void k_sumexp(const bf16_t* __restrict__ hbf,
                                                const bf16_t* __restrict__ woutT,
                                                const float* __restrict__ bout,
                                                float* __restrict__ gsums) {
  const int t = threadIdx.x;
  const int lane = t & 63, wave = t >> 6;
  const int row0 = blockIdx.y * 64;
  const int nbase = blockIdx.x * 4000;
  const int mrow = lane & 15, quad = lane >> 4;
  __shared__ float lsum[64];
  if (t < 64) lsum[t] = 0.f;
  __syncthreads();

  bf16x8 a0[4], a1[4];
#pragma unroll
  for (int at = 0; at < 4; ++at) {
    const bf16_t* arow = hbf + (size_t)(row0 + at * 16 + mrow) * 64 + quad * 8;
    a0[at] = *(const bf16x8*)(arow);
    a1[at] = *(const bf16x8*)(arow + 32);
  }

  float s[4][4];
#pragma unroll
  for (int at = 0; at < 4; ++at)
#pragma unroll
    for (int r = 0; r < 4; ++r) s[at][r] = 0.f;

  for (int tt = wave; tt < 250; tt += 4) {
    int col = nbase + tt * 16 + mrow;
    const bf16_t* brow = woutT + (size_t)col * 64 + quad * 8;
    bf16x8 b0 = *(const bf16x8*)(brow);
    bf16x8 b1 = *(const bf16x8*)(brow + 32);
    float bv = bout[col];
#pragma unroll
    for (int at = 0; at < 4; ++at) {
      f32x4 c = {0.f, 0.f, 0.f, 0.f};
      c = __builtin_amdgcn_mfma_f32_16x16x32_bf16(a0[at], b0, c, 0, 0, 0);
      c = __builtin_amdgcn_mfma_f32_16x16x32_bf16(a1[at], b1, c, 0, 0, 0);
      s[at][0] += __expf(c[0] + bv);
      s[at][1] += __expf(c[1] + bv);
      s[at][2] += __expf(c[2] + bv);
      s[at][3] += __expf(c[3] + bv);
    }
  }
  // reduce over the 16 lanes of each quad (C cols); rows = at*16 + quad*4 + reg
#pragma unroll
  for (int off = 1; off < 16; off <<= 1) {
#pragma unroll
    for (int at = 0; at < 4; ++at) {
      s[at][0] += __shfl_xor(s[at][0], off, 64);
      s[at][1] += __shfl_xor(s[at][1], off, 64);
      s[at][2] += __shfl_xor(s[at][2], off, 64);
      s[at][3] += __shfl_xor(s[at][3], off, 64);
    }
  }
  if (mrow == 0) {
#pragma unroll
    for (int at = 0; at < 4; ++at) {
      atomicAdd(&lsum[at * 16 + quad * 4 + 0], s[at][0]);
      atomicAdd(&lsum[at * 16 + quad * 4 + 1], s[at][1]);
      atomicAdd(&lsum[at * 16 + quad * 4 + 2], s[at][2]);
      atomicAdd(&lsum[at * 16 + quad * 4 + 3], s[at][3]);
    }
  }
  __syncthreads();
  if (t < 64) atomicAdd(&gsums[row0 + t], lsum[t]);
}

// ---------- kernel B: recompute logits, write rint(exp(l)*inv_sum) ----------
// grid (8, 64), nontemporal output stores (keep woutT slice L2-resident)
__global__ __launch_bounds__(256) void k_probs(const bf16_t* __restrict__ hbf,
                                               const bf16_t* __restrict__ woutT,
                                               const float* __restrict__ bout,
                                               const float* __restrict__ gsums,
                                               float* __restrict__ out) {
  const int t = threadIdx.x;
  const int lane = t & 63, wave = t >> 6;
  const int row0 = blockIdx.y * 64;
  const int nbase = blockIdx.x * 4000;
  const int mrow = lane & 15, quad = lane >> 4;
  __shared__ float linv[64];
  if (t < 64) linv[t] = 1.0f / gsums[row0 + t];
  __syncthreads();

  bf16x8 a0[4], a1[4];
#pragma unroll
  for (int at = 0; at < 4; ++at) {
    const bf16_t* arow = hbf + (size_t)(row0 + at * 16 + mrow) * 64 + quad * 8;
    a0[at] = *(const bf16x8*)(arow);
    a1[at] = *(const bf16x8*)(arow + 32);
  }

  float iv[4][4];
  size_t ob[4][4];
#pragma unroll
  for (int at = 0; at < 4; ++at)
#pragma unroll
    for (int r = 0; r < 4; ++r) {
      iv[at][r] = linv[at * 16 + quad * 4 + r];
      ob[at][r] = (size_t)(row0 + at * 16 + quad * 4 + r) * VOC;
    }

  for (int tt = wave; tt < 250; tt += 4) {
    int col = nbase + tt * 16 + mrow;
    const bf16_t* brow = woutT + (size_t)col * 64 + quad * 8;
    bf16x8 b0 = *(const bf16x8*)(brow);
    bf16x8 b1 = *(const bf16x8*)(brow + 32);
    float bv = bout[col];
#pragma unroll
    for (int at = 0; at < 4; ++at) {
      f32x4 c = {0.f, 0.f, 0.f, 0.f};
      c = __builtin_amdgcn_mfma_f32_16x16x32_bf16(a0[at], b0, c, 0, 0, 0);
      c = __builtin_amdgcn_mfma_f32_16x16x32_bf16(a1[at], b1, c, 0, 0, 0);
      __builtin_nontemporal_store(rintf(__expf(c[0] + bv) * iv[at][0]), &out[ob[at][0] + col]);
      __builtin_nontemporal_store(rintf(__expf(c[1] + bv) * iv[at][1]), &out[ob[at][1] + col]);
      __builtin_nontemporal_store(rintf(__expf(c[2] + bv) * iv[at][2]), &out[ob[at][2] + col]);
      __builtin_nontemporal_store(rintf(__expf(c[3] + bv) * iv[at][3]), &out[ob[at][3] + col]);
    }
  }
}

extern "C" void kernel_launch(void* const* d_in, const int* in_sizes, int n_in,
                              void* d_out, int out_size, void* d_ws, size_t ws_size,
                              hipStream_t stream) {
  const int* x = (const int*)d_in[0];
  const float* emb = (const float*)d_in[1];
  const float* pe = (const float*)d_in[2];
  const float* wq = (const float*)d_in[3];
  const float* wk = (const float*)d_in[4];
  const float* wv = (const float*)d_in[5];
  const float* g_h = (const float*)d_in[6];
  const float* b_h = (const float*)d_in[7];
  const float* wo = (const float*)d_in[8];
  const float* bo = (const float*)d_in[9];
  const float* g1 = (const float*)d_in[10];
  const float* bt1 = (const float*)d_in[11];
  const float* w1 = (const float*)d_in[12];
  const float* b1f = (const float*)d_in[13];
  const float* w2 = (const float*)d_in[14];
  const float* b2f = (const float*)d_in[15];
  const float* g2 = (const float*)d_in[16];
  const float* bt2 = (const float*)d_in[17];
  const float* gf = (const float*)d_in[18];
  const float* bff = (const float*)d_in[19];
  const float* wout = (const float*)d_in[20];
  const float* bout = (const float*)d_in[21];

  char* ws = (char*)d_ws;
  bf16_t* woutT = (bf16_t*)(ws + WOUTT_OFF);
  bf16_t* hbf = (bf16_t*)(ws + HBF_OFF);
  float* gsums = (float*)(ws + GSUM_OFF);
  float* out = (float*)d_out;

  k_woutT<<<500, 256, 0, stream>>>(wout, woutT);
  k_former<<<64, 256, 0, stream>>>(x, emb, pe, wq, wk, wv, g_h, b_h, wo, bo,
                                   g1, bt1, w1, b1f, w2, b2f, g2, bt2, gf, bff,
                                   hbf, gsums);
  dim3 grid(8, 64);
  k_sumexp<<<grid, 256, 0, stream>>>(hbf, woutT, bout, gsums);
  k_probs<<<grid, 256, 0, stream>>>(hbf, woutT, bout, gsums, out);
}

// Round 4
// 954.815 us; speedup vs baseline: 1.0401x; 1.0401x over previous
//
#include <hip/hip_runtime.h>
#include <hip/hip_bf16.h>
#include <math.h>

#define EMB 64
#define SEQ 64
#define NH 8
#define DFF 256
#define VOC 32000
#define BATCH 64

using bf16_t = __hip_bfloat16;
typedef __bf16 bf16x8 __attribute__((ext_vector_type(8)));
typedef float f32x4 __attribute__((ext_vector_type(4)));

// ws layout (bytes)
#define WOUTT_OFF 0                     // bf16 [32000][64]  = 4,096,000 B
#define HBF_OFF   4194304               // bf16 [4096][64]   = 524,288 B
#define GSUM_OFF  (4194304 + 524288)    // f32  [4096]       = 16,384 B

// ---------- small 64x64x64 GEMM helper: out = in(LDS,ld 65) @ W(global 64x64) ----------
template <int OP>  // 0: none, 1: rint
__device__ inline void gemm64t(const float* __restrict__ in, const float* __restrict__ W,
                               const float* __restrict__ bias, float* __restrict__ out,
                               int t) {
  int i = t >> 2, j0 = (t & 3) * 16;
  float acc[16];
#pragma unroll
  for (int j = 0; j < 16; ++j) acc[j] = 0.f;
  for (int k = 0; k < 64; ++k) {
    float a = in[i * 65 + k];
    const float4* wr = (const float4*)(W + k * 64 + j0);
    float4 w0 = wr[0], w1v = wr[1], w2v = wr[2], w3v = wr[3];
    acc[0] += a * w0.x;   acc[1] += a * w0.y;   acc[2] += a * w0.z;   acc[3] += a * w0.w;
    acc[4] += a * w1v.x;  acc[5] += a * w1v.y;  acc[6] += a * w1v.z;  acc[7] += a * w1v.w;
    acc[8] += a * w2v.x;  acc[9] += a * w2v.y;  acc[10] += a * w2v.z; acc[11] += a * w2v.w;
    acc[12] += a * w3v.x; acc[13] += a * w3v.y; acc[14] += a * w3v.z; acc[15] += a * w3v.w;
  }
#pragma unroll
  for (int j = 0; j < 16; ++j) {
    float v = acc[j] + (bias ? bias[j0 + j] : 0.f);
    if (OP == 1) v = rintf(v);
    out[i * 65 + j0 + j] = v;
  }
}

// ---------- fused kernel: blocks 0..63 run the transformer (b = blockIdx.x);
// blocks 64..563 transpose wout -> woutT bf16. Independent work, overlapped. ----------
__global__ __launch_bounds__(256) void k_prep(
    const int* __restrict__ x, const float* __restrict__ emb, const float* __restrict__ pe,
    const float* __restrict__ wq, const float* __restrict__ wk, const float* __restrict__ wv,
    const float* __restrict__ g_h, const float* __restrict__ b_h,
    const float* __restrict__ wo, const float* __restrict__ bo,
    const float* __restrict__ g1, const float* __restrict__ bt1,
    const float* __restrict__ w1, const float* __restrict__ b1f,
    const float* __restrict__ w2, const float* __restrict__ b2f,
    const float* __restrict__ g2, const float* __restrict__ bt2,
    const float* __restrict__ gf, const float* __restrict__ bf_,
    const float* __restrict__ wout, bf16_t* __restrict__ woutT,
    bf16_t* __restrict__ hbf, float* __restrict__ gsums) {
  const int t = threadIdx.x;
  __shared__ float sm[6 * 64 * 65];   // 99.84 KB

  if (blockIdx.x >= 64) {
    // ---- transpose path: wout [64][32000] f32 -> woutT [32000][64] bf16 ----
    float* tile = sm;  // [64][65]
    int v0 = (blockIdx.x - 64) * 64;
    for (int idx = t; idx < 4096; idx += 256) {
      int e = idx >> 6, c = idx & 63;
      tile[e * 65 + c] = wout[(size_t)e * VOC + v0 + c];
    }
    __syncthreads();
    for (int idx = t; idx < 4096; idx += 256) {
      int c = idx >> 6, e = idx & 63;
      woutT[(size_t)(v0 + c) * 64 + e] = __float2bfloat16(tile[e * 65 + c]);
    }
    return;
  }

  // ---- transformer path ----
  const int b = blockIdx.x;
  if (t < 64) gsums[b * 64 + t] = 0.f;  // zero row-sum accumulators

  float* Hs = sm;                      // [64][65]
  float* Qs = sm + 4160;
  float* Ks = sm + 2 * 4160;
  float* Vs = sm + 3 * 4160;
  float* SC = sm + 4 * 4160;
  float* HO = sm + 5 * 4160;
  float* MID = sm + 4160;              // [64][260] overlays Qs..SC (16640 floats)

  // Stage 0: h = emb[x[b]] + pe
  for (int idx = t; idx < 4096; idx += 256) {
    int i = idx >> 6, e = idx & 63;
    int tok = x[b * 64 + i];
    Hs[i * 65 + e] = emb[(size_t)tok * 64 + e] + pe[i * 64 + e];
  }
  __syncthreads();

  // Stage 1: Q, K, V
  gemm64t<0>(Hs, wq, nullptr, Qs, t);
  gemm64t<0>(Hs, wk, nullptr, Ks, t);
  gemm64t<0>(Hs, wv, nullptr, Vs, t);
  __syncthreads();

  // Stage 2: attention per head (causal softmax, round4 on head outputs)
  const float scale = 0.35355339059327373f;  // 1/sqrt(8)
  for (int hh = 0; hh < NH; ++hh) {
    int qc = hh * 8;
    {
      int i = t >> 2, jb = t & 3;
      float qv[8];
#pragma unroll
      for (int d = 0; d < 8; ++d) qv[d] = Qs[i * 65 + qc + d];
      for (int jj = 0; jj < 16; ++jj) {
        int j = jb * 16 + jj;
        float s;
        if (j <= i) {
          s = 0.f;
#pragma unroll
          for (int d = 0; d < 8; ++d) s += qv[d] * Ks[j * 65 + qc + d];
          s *= scale;
        } else {
          s = -INFINITY;
        }
        SC[i * 65 + j] = s;
      }
    }
    __syncthreads();
    if (t < 64) {
      int i = t;
      float m = -INFINITY;
      for (int j = 0; j <= i; ++j) m = fmaxf(m, SC[i * 65 + j]);
      float sum = 0.f;
      for (int j = 0; j <= i; ++j) {
        float e2 = __expf(SC[i * 65 + j] - m);
        SC[i * 65 + j] = e2;
        sum += e2;
      }
      float inv = 1.f / sum;
      for (int j = 0; j <= i; ++j) SC[i * 65 + j] *= inv;
      for (int j = i + 1; j < 64; ++j) SC[i * 65 + j] = 0.f;
    }
    __syncthreads();
    for (int idx = t; idx < 512; idx += 256) {
      int i = idx >> 3, d = idx & 7;
      float o = 0.f;
      for (int j = 0; j < 64; ++j) o += SC[i * 65 + j] * Vs[j * 65 + qc + d];
      HO[i * 65 + qc + d] = rintf(o * 1e4f) / 1e4f;  // round4
    }
    __syncthreads();
  }

  // Stage 3: ln_h = layernorm(HO; g_h,b_h) -> SC ; attn_out = rint(SC@wo+bo) -> HO
  if (t < 64) {
    int i = t;
    float mu = 0.f;
    for (int e = 0; e < 64; ++e) mu += HO[i * 65 + e];
    mu *= (1.f / 64.f);
    float var = 0.f;
    for (int e = 0; e < 64; ++e) { float d = HO[i * 65 + e] - mu; var += d * d; }
    var *= (1.f / 64.f);
    float rs = rsqrtf(var + 1e-5f);
    for (int e = 0; e < 64; ++e) SC[i * 65 + e] = (HO[i * 65 + e] - mu) * rs * g_h[e] + b_h[e];
  }
  __syncthreads();
  gemm64t<1>(SC, wo, bo, HO, t);
  __syncthreads();

  // Stage 4: h1 = layernorm(Hs + HO; g1,bt1) -> Hs
  if (t < 64) {
    int i = t;
    for (int e = 0; e < 64; ++e) Hs[i * 65 + e] += HO[i * 65 + e];
    float mu = 0.f;
    for (int e = 0; e < 64; ++e) mu += Hs[i * 65 + e];
    mu *= (1.f / 64.f);
    float var = 0.f;
    for (int e = 0; e < 64; ++e) { float d = Hs[i * 65 + e] - mu; var += d * d; }
    var *= (1.f / 64.f);
    float rs = rsqrtf(var + 1e-5f);
    for (int e = 0; e < 64; ++e) Hs[i * 65 + e] = (Hs[i * 65 + e] - mu) * rs * g1[e] + bt1[e];
  }
  __syncthreads();

  // Stage 5: MID = relu(Hs @ w1 + b1f)  [64][260 pad]
  {
    int i = t >> 2, jq = t & 3;
    for (int c = 0; c < 4; ++c) {
      int j0 = jq * 64 + c * 16;
      float acc[16];
#pragma unroll
      for (int j = 0; j < 16; ++j) acc[j] = 0.f;
      for (int k = 0; k < 64; ++k) {
        float a = Hs[i * 65 + k];
        const float4* wr = (const float4*)(w1 + (size_t)k * 256 + j0);
        float4 w0 = wr[0], w1v = wr[1], w2v = wr[2], w3v = wr[3];
        acc[0] += a * w0.x;   acc[1] += a * w0.y;   acc[2] += a * w0.z;   acc[3] += a * w0.w;
        acc[4] += a * w1v.x;  acc[5] += a * w1v.y;  acc[6] += a * w1v.z;  acc[7] += a * w1v.w;
        acc[8] += a * w2v.x;  acc[9] += a * w2v.y;  acc[10] += a * w2v.z; acc[11] += a * w2v.w;
        acc[12] += a * w3v.x; acc[13] += a * w3v.y; acc[14] += a * w3v.z; acc[15] += a * w3v.w;
      }
#pragma unroll
      for (int j = 0; j < 16; ++j)
        MID[i * 260 + j0 + j] = fmaxf(acc[j] + b1f[j0 + j], 0.f);
    }
  }
  __syncthreads();

  // Stage 6: ffn_out = MID @ w2 + b2f -> HO
  {
    int i = t >> 2, j0 = (t & 3) * 16;
    float acc[16];
#pragma unroll
    for (int j = 0; j < 16; ++j) acc[j] = 0.f;
    for (int k = 0; k < 256; ++k) {
      float a = MID[i * 260 + k];
      const float4* wr = (const float4*)(w2 + (size_t)k * 64 + j0);
      float4 w0 = wr[0], w1v = wr[1], w2v = wr[2], w3v = wr[3];
      acc[0] += a * w0.x;   acc[1] += a * w0.y;   acc[2] += a * w0.z;   acc[3] += a * w0.w;
      acc[4] += a * w1v.x;  acc[5] += a * w1v.y;  acc[6] += a * w1v.z;  acc[7] += a * w1v.w;
      acc[8] += a * w2v.x;  acc[9] += a * w2v.y;  acc[10] += a * w2v.z; acc[11] += a * w2v.w;
      acc[12] += a * w3v.x; acc[13] += a * w3v.y; acc[14] += a * w3v.z; acc[15] += a * w3v.w;
    }
#pragma unroll
    for (int j = 0; j < 16; ++j) HO[i * 65 + j0 + j] = acc[j] + b2f[j0 + j];
  }
  __syncthreads();

  // Stage 7: h2 = round4(layernorm(Hs + HO; g2,bt2)) -> Hs ; hf = layernorm(Hs; gf,bf) -> SC
  if (t < 64) {
    int i = t;
    for (int e = 0; e < 64; ++e) Hs[i * 65 + e] += HO[i * 65 + e];
    float mu = 0.f;
    for (int e = 0; e < 64; ++e) mu += Hs[i * 65 + e];
    mu *= (1.f / 64.f);
    float var = 0.f;
    for (int e = 0; e < 64; ++e) { float d = Hs[i * 65 + e] - mu; var += d * d; }
    var *= (1.f / 64.f);
    float rs = rsqrtf(var + 1e-5f);
    for (int e = 0; e < 64; ++e)
      Hs[i * 65 + e] = rintf(((Hs[i * 65 + e] - mu) * rs * g2[e] + bt2[e]) * 1e4f) / 1e4f;
    float mu2 = 0.f;
    for (int e = 0; e < 64; ++e) mu2 += Hs[i * 65 + e];
    mu2 *= (1.f / 64.f);
    float var2 = 0.f;
    for (int e = 0; e < 64; ++e) { float d = Hs[i * 65 + e] - mu2; var2 += d * d; }
    var2 *= (1.f / 64.f);
    float rs2 = rsqrtf(var2 + 1e-5f);
    for (int e = 0; e < 64; ++e) SC[i * 65 + e] = (Hs[i * 65 + e] - mu2) * rs2 * gf[e] + bf_[e];
  }
  __syncthreads();

  // Stage 8: hf -> bf16 global
  for (int idx = t; idx < 4096; idx += 256) {
    int i = idx >> 6, e = idx & 63;
    hbf[((size_t)b * 64 + i) * 64 + e] = __float2bfloat16(SC[i * 65 + e]);
  }
}

// ---------- kernel A: per-row sum of exp(logit) over V, MFMA recompute ----------
// 64 rows per block (4 A-row-tiles share each B-tile load): grid (64, 8)
__global__ __launch_bounds__(256) void k_sumexp(const bf16_t* __restrict__ hbf,
                                                const bf16_t* __restrict__ woutT,
                                                const float* __restrict__ bout,
                                                float* __restrict__ gsums) {
  const int t = threadIdx.x;
  const int lane = t & 63, wave = t >> 6;
  const int row0 = blockIdx.x * 64;
  const int nbase = blockIdx.y * 4000;
  const int mrow = lane & 15, quad = lane >> 4;
  __shared__ float lsum[64];
  if (t < 64) lsum[t] = 0.f;
  __syncthreads();

  bf16x8 a0[4], a1[4];
#pragma unroll
  for (int at = 0; at < 4; ++at) {
    const bf16_t* arow = hbf + (size_t)(row0 + at * 16 + mrow) * 64 + quad * 8;
    a0[at] = *(const bf16x8*)(arow);
    a1[at] = *(const bf16x8*)(arow + 32);
  }

  float s[4][4];
#pragma unroll
  for (int at = 0; at < 4; ++at)
#pragma unroll
    for (int r = 0; r < 4; ++r) s[at][r] = 0.f;

  for (int tt = wave; tt < 250; tt += 4) {
    int col = nbase + tt * 16 + mrow;
    const bf16_t* brow = woutT + (size_t)col * 64 + quad * 8;
    bf16x8 b0 = *(const bf16x8*)(brow);
    bf16x8 b1 = *(const bf16x8*)(brow + 32);
    float bv = bout[col];
#pragma unroll
    for (int at = 0; at < 4; ++at) {
      f32x4 c = {0.f, 0.f, 0.f, 0.f};
      c = __builtin_amdgcn_mfma_f32_16x16x32_bf16(a0[at], b0, c, 0, 0, 0);
      c = __builtin_amdgcn_mfma_f32_16x16x32_bf16(a1[at], b1, c, 0, 0, 0);
      s[at][0] += __expf(c[0] + bv);
      s[at][1] += __expf(c[1] + bv);
      s[at][2] += __expf(c[2] + bv);
      s[at][3] += __expf(c[3] + bv);
    }
  }
  // reduce over the 16 lanes of each quad (C cols); rows = at*16 + quad*4 + reg
#pragma unroll
  for (int off = 1; off < 16; off <<= 1) {
#pragma unroll
    for (int at = 0; at < 4; ++at) {
      s[at][0] += __shfl_xor(s[at][0], off, 64);
      s[at][1] += __shfl_xor(s[at][1], off, 64);
      s[at][2] += __shfl_xor(s[at][2], off, 64);
      s[at][3] += __shfl_xor(s[at][3], off, 64);
    }
  }
  if (mrow == 0) {
#pragma unroll
    for (int at = 0; at < 4; ++at) {
      atomicAdd(&lsum[at * 16 + quad * 4 + 0], s[at][0]);
      atomicAdd(&lsum[at * 16 + quad * 4 + 1], s[at][1]);
      atomicAdd(&lsum[at * 16 + quad * 4 + 2], s[at][2]);
      atomicAdd(&lsum[at * 16 + quad * 4 + 3], s[at][3]);
    }
  }
  __syncthreads();
  if (t < 64) atomicAdd(&gsums[row0 + t], lsum[t]);
}

// ---------- kernel B: recompute logits, write rint(exp(l)*inv_sum) ----------
// 64 rows per block: grid (64, 8)
__global__ __launch_bounds__(256) void k_probs(const bf16_t* __restrict__ hbf,
                                               const bf16_t* __restrict__ woutT,
                                               const float* __restrict__ bout,
                                               const float* __restrict__ gsums,
                                               float* __restrict__ out) {
  const int t = threadIdx.x;
  const int lane = t & 63, wave = t >> 6;
  const int row0 = blockIdx.x * 64;
  const int nbase = blockIdx.y * 4000;
  const int mrow = lane & 15, quad = lane >> 4;
  __shared__ float linv[64];
  if (t < 64) linv[t] = 1.0f / gsums[row0 + t];
  __syncthreads();

  bf16x8 a0[4], a1[4];
#pragma unroll
  for (int at = 0; at < 4; ++at) {
    const bf16_t* arow = hbf + (size_t)(row0 + at * 16 + mrow) * 64 + quad * 8;
    a0[at] = *(const bf16x8*)(arow);
    a1[at] = *(const bf16x8*)(arow + 32);
  }

  float iv[4][4];
  size_t ob[4][4];
#pragma unroll
  for (int at = 0; at < 4; ++at)
#pragma unroll
    for (int r = 0; r < 4; ++r) {
      iv[at][r] = linv[at * 16 + quad * 4 + r];
      ob[at][r] = (size_t)(row0 + at * 16 + quad * 4 + r) * VOC;
    }

  for (int tt = wave; tt < 250; tt += 4) {
    int col = nbase + tt * 16 + mrow;
    const bf16_t* brow = woutT + (size_t)col * 64 + quad * 8;
    bf16x8 b0 = *(const bf16x8*)(brow);
    bf16x8 b1 = *(const bf16x8*)(brow + 32);
    float bv = bout[col];
#pragma unroll
    for (int at = 0; at < 4; ++at) {
      f32x4 c = {0.f, 0.f, 0.f, 0.f};
      c = __builtin_amdgcn_mfma_f32_16x16x32_bf16(a0[at], b0, c, 0, 0, 0);
      c = __builtin_amdgcn_mfma_f32_16x16x32_bf16(a1[at], b1, c, 0, 0, 0);
      out[ob[at][0] + col] = rintf(__expf(c[0] + bv) * iv[at][0]);
      out[ob[at][1] + col] = rintf(__expf(c[1] + bv) * iv[at][1]);
      out[ob[at][2] + col] = rintf(__expf(c[2] + bv) * iv[at][2]);
      out[ob[at][3] + col] = rintf(__expf(c[3] + bv) * iv[at][3]);
    }
  }
}

extern "C" void kernel_launch(void* const* d_in, const int* in_sizes, int n_in,
                              void* d_out, int out_size, void* d_ws, size_t ws_size,
                              hipStream_t stream) {
  const int* x = (const int*)d_in[0];
  const float* emb = (const float*)d_in[1];
  const float* pe = (const float*)d_in[2];
  const float* wq = (const float*)d_in[3];
  const float* wk = (const float*)d_in[4];
  const float* wv = (const float*)d_in[5];
  const float* g_h = (const float*)d_in[6];
  const float* b_h = (const float*)d_in[7];
  const float* wo = (const float*)d_in[8];
  const float* bo = (const float*)d_in[9];
  const float* g1 = (const float*)d_in[10];
  const float* bt1 = (const float*)d_in[11];
  const float* w1 = (const float*)d_in[12];
  const float* b1f = (const float*)d_in[13];
  const float* w2 = (const float*)d_in[14];
  const float* b2f = (const float*)d_in[15];
  const float* g2 = (const float*)d_in[16];
  const float* bt2 = (const float*)d_in[17];
  const float* gf = (const float*)d_in[18];
  const float* bff = (const float*)d_in[19];
  const float* wout = (const float*)d_in[20];
  const float* bout = (const float*)d_in[21];

  char* ws = (char*)d_ws;
  bf16_t* woutT = (bf16_t*)(ws + WOUTT_OFF);
  bf16_t* hbf = (bf16_t*)(ws + HBF_OFF);
  float* gsums = (float*)(ws + GSUM_OFF);
  float* out = (float*)d_out;

  k_prep<<<564, 256, 0, stream>>>(x, emb, pe, wq, wk, wv, g_h, b_h, wo, bo,
                                  g1, bt1, w1, b1f, w2, b2f, g2, bt2, gf, bff,
                                  wout, woutT, hbf, gsums);
  dim3 grid(64, 8);
  k_sumexp<<<grid, 256, 0, stream>>>(hbf, woutT, bout, gsums);
  k_probs<<<grid, 256, 0, stream>>>(hbf, woutT, bout, gsums, out);
}